// Round 1
// baseline (2752.328 us; speedup 1.0000x reference)
//
#include <hip/hip_runtime.h>

typedef __attribute__((ext_vector_type(8))) short bf16x8_t;
typedef __attribute__((ext_vector_type(4))) float f32x4_t;

constexpr int NG = 16;          // num_graphs (fixed by harness inputs)
constexpr float EPS = 1e-5f;

__device__ inline unsigned short f2bf(float f) {
  unsigned u = __builtin_bit_cast(unsigned, f);
  u += 0x7FFFu + ((u >> 16) & 1u);   // RNE (data is finite; no NaN handling needed)
  return (unsigned short)(u >> 16);
}

__device__ inline bf16x8_t pack8(float4 a, float4 b) {
  bf16x8_t r;
  r[0] = (short)f2bf(a.x); r[1] = (short)f2bf(a.y);
  r[2] = (short)f2bf(a.z); r[3] = (short)f2bf(a.w);
  r[4] = (short)f2bf(b.x); r[5] = (short)f2bf(b.y);
  r[6] = (short)f2bf(b.z); r[7] = (short)f2bf(b.w);
  return r;
}

// ---------------- edge update: e_out = e_in + [x_s|x_d|e_in] @ W(320x64) + b --------
// NOTE: e_in/e_out alias in layer 1 -> no __restrict__ on them.
__global__ __launch_bounds__(256) void k_mm_edge(
    const float* __restrict__ x, const float* e_in, float* e_out,
    const int* __restrict__ ei, const unsigned short* __restrict__ Wt,
    const float* __restrict__ bias, int nE)
{
  int gw = (int)((blockIdx.x * (unsigned)blockDim.x + threadIdx.x) >> 6);
  int ntile = nE >> 4;
  if (gw >= ntile) return;
  int lane = threadIdx.x & 63;
  int colb = lane & 15;
  int row  = (gw << 4) + colb;          // A-row this lane supplies
  int ko   = (lane >> 4) << 3;          // k offset within 32-chunk
  int s = ei[row], d = ei[nE + row];
  const float* xs = x + (size_t)s * 128;
  const float* xd = x + (size_t)d * 128;
  const float* er = e_in + (size_t)row * 64;
  f32x4_t acc[4] = {};
#pragma unroll
  for (int c = 0; c < 10; ++c) {
    const float* bp = (c < 4) ? (xs + c * 32) : (c < 8) ? (xd + (c - 4) * 32) : (er + (c - 8) * 32);
    float4 f0 = *(const float4*)(bp + ko);
    float4 f1 = *(const float4*)(bp + ko + 4);
    bf16x8_t a = pack8(f0, f1);
#pragma unroll
    for (int nb = 0; nb < 4; ++nb) {
      bf16x8_t b = *(const bf16x8_t*)(Wt + (size_t)(nb * 16 + colb) * 320 + c * 32 + ko);
      acc[nb] = __builtin_amdgcn_mfma_f32_16x16x32_bf16(a, b, acc[nb], 0, 0, 0);
    }
  }
  int rowb = (lane >> 4) << 2;
#pragma unroll
  for (int nb = 0; nb < 4; ++nb)
#pragma unroll
    for (int r = 0; r < 4; ++r) {
      int e_ = (gw << 4) + rowb + r;
      int col = nb * 16 + colb;
      size_t off = (size_t)e_ * 64 + col;
      e_out[off] = e_in[off] + bias[col] + acc[nb][r];
    }
}

// ---------------- angle update: a_out = a_in + [e_s|e_d|a_in] @ W(192x64) + b -------
__global__ __launch_bounds__(256) void k_mm_angle(
    const float* __restrict__ e, const float* a_in, float* a_out,
    const int* __restrict__ ti, const unsigned short* __restrict__ Wt,
    const float* __restrict__ bias, int nA)
{
  int gw = (int)((blockIdx.x * (unsigned)blockDim.x + threadIdx.x) >> 6);
  int ntile = nA >> 4;
  if (gw >= ntile) return;
  int lane = threadIdx.x & 63;
  int colb = lane & 15;
  int row  = (gw << 4) + colb;
  int ko   = (lane >> 4) << 3;
  int s = ti[row], d = ti[nA + row];
  const float* es = e + (size_t)s * 64;
  const float* ed = e + (size_t)d * 64;
  const float* ar = a_in + (size_t)row * 64;
  f32x4_t acc[4] = {};
#pragma unroll
  for (int c = 0; c < 6; ++c) {
    const float* bp = (c < 2) ? (es + c * 32) : (c < 4) ? (ed + (c - 2) * 32) : (ar + (c - 4) * 32);
    float4 f0 = *(const float4*)(bp + ko);
    float4 f1 = *(const float4*)(bp + ko + 4);
    bf16x8_t a = pack8(f0, f1);
#pragma unroll
    for (int nb = 0; nb < 4; ++nb) {
      bf16x8_t b = *(const bf16x8_t*)(Wt + (size_t)(nb * 16 + colb) * 192 + c * 32 + ko);
      acc[nb] = __builtin_amdgcn_mfma_f32_16x16x32_bf16(a, b, acc[nb], 0, 0, 0);
    }
  }
  int rowb = (lane >> 4) << 2;
#pragma unroll
  for (int nb = 0; nb < 4; ++nb)
#pragma unroll
    for (int r = 0; r < 4; ++r) {
      int a_ = (gw << 4) + rowb + r;
      int col = nb * 16 + colb;
      size_t off = (size_t)a_ * 64 + col;
      a_out[off] = a_in[off] + bias[col] + acc[nb][r];
    }
}

// ------------- edge_graph_mp: msg = relu([e_s|e_d|a] @ W(192x64) + b); agg[dst_t] += msg
__global__ __launch_bounds__(256) void k_mm_emp(
    const float* __restrict__ e, const float* __restrict__ a_,
    const int* __restrict__ ti, const unsigned short* __restrict__ Wt,
    const float* __restrict__ bias, float* __restrict__ agg, int nA)
{
  int gw = (int)((blockIdx.x * (unsigned)blockDim.x + threadIdx.x) >> 6);
  int ntile = nA >> 4;
  if (gw >= ntile) return;
  int lane = threadIdx.x & 63;
  int colb = lane & 15;
  int row  = (gw << 4) + colb;
  int ko   = (lane >> 4) << 3;
  int s = ti[row], d = ti[nA + row];
  const float* es = e + (size_t)s * 64;
  const float* ed = e + (size_t)d * 64;
  const float* ar = a_ + (size_t)row * 64;
  f32x4_t acc[4] = {};
#pragma unroll
  for (int c = 0; c < 6; ++c) {
    const float* bp = (c < 2) ? (es + c * 32) : (c < 4) ? (ed + (c - 2) * 32) : (ar + (c - 4) * 32);
    float4 f0 = *(const float4*)(bp + ko);
    float4 f1 = *(const float4*)(bp + ko + 4);
    bf16x8_t a = pack8(f0, f1);
#pragma unroll
    for (int nb = 0; nb < 4; ++nb) {
      bf16x8_t b = *(const bf16x8_t*)(Wt + (size_t)(nb * 16 + colb) * 192 + c * 32 + ko);
      acc[nb] = __builtin_amdgcn_mfma_f32_16x16x32_bf16(a, b, acc[nb], 0, 0, 0);
    }
  }
  int rowb = (lane >> 4) << 2;
#pragma unroll
  for (int nb = 0; nb < 4; ++nb)
#pragma unroll
    for (int r = 0; r < 4; ++r) {
      int a_idx = (gw << 4) + rowb + r;
      int dst = ti[nA + a_idx];
      int col = nb * 16 + colb;
      float v = fmaxf(acc[nb][r] + bias[col], 0.f);
      atomicAdd(&agg[(size_t)dst * 64 + col], v);
    }
}

// ------------- node_graph_mp: msg = relu([x_s|x_d|e] @ W(320x128) + b); agg[dst_e] += msg
__global__ __launch_bounds__(256) void k_mm_nmp(
    const float* __restrict__ x, const float* __restrict__ e,
    const int* __restrict__ ei, const unsigned short* __restrict__ Wt,
    const float* __restrict__ bias, float* __restrict__ agg, int nE)
{
  int gw = (int)((blockIdx.x * (unsigned)blockDim.x + threadIdx.x) >> 6);
  int ntile = nE >> 4;
  if (gw >= ntile) return;
  int lane = threadIdx.x & 63;
  int colb = lane & 15;
  int row  = (gw << 4) + colb;
  int ko   = (lane >> 4) << 3;
  int s = ei[row], d = ei[nE + row];
  const float* xs = x + (size_t)s * 128;
  const float* xd = x + (size_t)d * 128;
  const float* er = e + (size_t)row * 64;
  f32x4_t acc[8] = {};
#pragma unroll
  for (int c = 0; c < 10; ++c) {
    const float* bp = (c < 4) ? (xs + c * 32) : (c < 8) ? (xd + (c - 4) * 32) : (er + (c - 8) * 32);
    float4 f0 = *(const float4*)(bp + ko);
    float4 f1 = *(const float4*)(bp + ko + 4);
    bf16x8_t a = pack8(f0, f1);
#pragma unroll
    for (int nb = 0; nb < 8; ++nb) {
      bf16x8_t b = *(const bf16x8_t*)(Wt + (size_t)(nb * 16 + colb) * 320 + c * 32 + ko);
      acc[nb] = __builtin_amdgcn_mfma_f32_16x16x32_bf16(a, b, acc[nb], 0, 0, 0);
    }
  }
  int rowb = (lane >> 4) << 2;
#pragma unroll
  for (int nb = 0; nb < 8; ++nb)
#pragma unroll
    for (int r = 0; r < 4; ++r) {
      int e_ = (gw << 4) + rowb + r;
      int dst = ei[nE + e_];
      int col = nb * 16 + colb;
      float v = fmaxf(acc[nb][r] + bias[col], 0.f);
      atomicAdd(&agg[(size_t)dst * 128 + col], v);
    }
}

// ------------- graph-norm stats: optional (h_out = h_in + addend); accumulate s1/s2 per graph
// h_in/h_out/addend may alias -> no __restrict__.
__global__ __launch_bounds__(256) void k_stats(
    const float* h_in, const float* addend, float* h_out,
    const int* __restrict__ batch, long total, int l2F,
    float* __restrict__ s1, float* __restrict__ s2)
{
  __shared__ float ls1[NG], ls2[NG];
  if (threadIdx.x < NG) { ls1[threadIdx.x] = 0.f; ls2[threadIdx.x] = 0.f; }
  __syncthreads();
  float a1 = 0.f, a2 = 0.f; int curg = -1;
  long stride = (long)gridDim.x * blockDim.x;
  for (long idx = (long)blockIdx.x * blockDim.x + threadIdx.x; idx < total; idx += stride) {
    float v = h_in[idx];
    if (addend) { v += addend[idx]; h_out[idx] = v; }
    int g = batch[idx >> l2F];
    if (g != curg) {
      if (curg >= 0) { atomicAdd(&ls1[curg], a1); atomicAdd(&ls2[curg], a2); }
      curg = g; a1 = 0.f; a2 = 0.f;
    }
    a1 += v; a2 += v * v;
  }
  if (curg >= 0) { atomicAdd(&ls1[curg], a1); atomicAdd(&ls2[curg], a2); }
  __syncthreads();
  if (threadIdx.x < NG) {
    atomicAdd(&s1[threadIdx.x], ls1[threadIdx.x]);
    atomicAdd(&s2[threadIdx.x], ls2[threadIdx.x]);
  }
}

// ------------- graph-norm apply: h = (h - mean_g) * rsqrt(var_g + eps) * w[f] + b[f]
__global__ __launch_bounds__(256) void k_gnorm(
    float* __restrict__ h, const int* __restrict__ batch, long total, int l2F,
    const float* __restrict__ s1, const float* __restrict__ s2,
    const float* __restrict__ cnt, const float* __restrict__ w, const float* __restrict__ b)
{
  __shared__ float lmean[NG], linv[NG];
  if (threadIdx.x < NG) {
    float F = (float)(1 << l2F);
    float norm = fmaxf(cnt[threadIdx.x], 1.f) * F;
    float m = s1[threadIdx.x] / norm;
    float v = s2[threadIdx.x] / norm - m * m;
    lmean[threadIdx.x] = m;
    linv[threadIdx.x] = rsqrtf(v + EPS);
  }
  __syncthreads();
  int mask = (1 << l2F) - 1;
  long stride = (long)gridDim.x * blockDim.x;
  for (long idx = (long)blockIdx.x * blockDim.x + threadIdx.x; idx < total; idx += stride) {
    int g = batch[idx >> l2F];
    int f = (int)(idx & mask);
    h[idx] = (h[idx] - lmean[g]) * linv[g] * w[f] + b[f];
  }
}

__global__ __launch_bounds__(256) void k_count(
    const int* __restrict__ batch, int n, float* __restrict__ cnt)
{
  __shared__ float lc[NG];
  if (threadIdx.x < NG) lc[threadIdx.x] = 0.f;
  __syncthreads();
  for (int i = blockIdx.x * blockDim.x + threadIdx.x; i < n; i += gridDim.x * blockDim.x)
    atomicAdd(&lc[batch[i]], 1.f);
  __syncthreads();
  if (threadIdx.x < NG) atomicAdd(&cnt[threadIdx.x], lc[threadIdx.x]);
}

// ------------- weight prep: W[k][j] (fp32) -> Wt[j][k] (bf16)
__global__ __launch_bounds__(256) void k_wt(
    const float* __restrict__ W, unsigned short* __restrict__ Wt, int K, int NO)
{
  int idx = blockIdx.x * blockDim.x + threadIdx.x;
  if (idx >= K * NO) return;
  int k = idx / NO, j = idx - k * NO;
  Wt[(size_t)j * K + k] = f2bf(W[idx]);
}

extern "C" void kernel_launch(void* const* d_in, const int* in_sizes, int n_in,
                              void* d_out, int out_size, void* d_ws, size_t ws_size,
                              hipStream_t stream)
{
  const float* x0    = (const float*)d_in[0];
  const float* e0    = (const float*)d_in[1];
  const float* a0    = (const float*)d_in[2];
  const float* W_ne  = (const float*)d_in[3];
  const float* b_ne  = (const float*)d_in[4];
  const float* g_e   = (const float*)d_in[5];
  const float* be_e  = (const float*)d_in[6];
  const float* W_ea  = (const float*)d_in[7];
  const float* b_ea  = (const float*)d_in[8];
  const float* g_a   = (const float*)d_in[9];
  const float* be_a  = (const float*)d_in[10];
  const float* W_emp = (const float*)d_in[11];
  const float* b_emp = (const float*)d_in[12];
  const float* g_emp = (const float*)d_in[13];
  const float* be_emp= (const float*)d_in[14];
  const float* W_nmp = (const float*)d_in[15];
  const float* b_nmp = (const float*)d_in[16];
  const float* g_nmp = (const float*)d_in[17];
  const float* be_nmp= (const float*)d_in[18];
  const int* node_batch  = (const int*)d_in[19];
  const int* edge_index  = (const int*)d_in[20];
  const int* edge_batch  = (const int*)d_in[21];
  const int* tb_index    = (const int*)d_in[22];
  const int* angle_batch = (const int*)d_in[23];

  const int N = in_sizes[0] / 128;
  const int E = in_sizes[1] / 64;
  const int A = in_sizes[2] / 64;

  float* ws    = (float*)d_ws;
  float* e_buf = ws;
  float* a_buf = e_buf + (size_t)E * 64;
  float* agg   = a_buf + (size_t)A * 64;          // reused: agg_e (E*64) then agg_n (N*128)
  float* s1    = agg + (size_t)E * 64;
  float* s2    = s1 + NG;
  float* cnt_n = s2 + NG;
  float* cnt_e = cnt_n + NG;
  float* cnt_a = cnt_e + NG;
  unsigned short* wt_ne  = (unsigned short*)(cnt_a + NG);
  unsigned short* wt_ea  = wt_ne  + 2 * 320 * 64;
  unsigned short* wt_emp = wt_ea  + 2 * 192 * 64;
  unsigned short* wt_nmp = wt_emp + 2 * 192 * 64;

  float* x_out = (float*)d_out;

  // weight transpose + bf16 convert (tiny)
  for (int i = 0; i < 2; ++i) {
    k_wt<<<(320 * 64 + 255) / 256, 256, 0, stream>>>(W_ne  + (size_t)i * 320 * 64,  wt_ne  + (size_t)i * 320 * 64,  320, 64);
    k_wt<<<(192 * 64 + 255) / 256, 256, 0, stream>>>(W_ea  + (size_t)i * 192 * 64,  wt_ea  + (size_t)i * 192 * 64,  192, 64);
    k_wt<<<(192 * 64 + 255) / 256, 256, 0, stream>>>(W_emp + (size_t)i * 192 * 64,  wt_emp + (size_t)i * 192 * 64,  192, 64);
    k_wt<<<(320 * 128 + 255) / 256, 256, 0, stream>>>(W_nmp + (size_t)i * 320 * 128, wt_nmp + (size_t)i * 320 * 128, 320, 128);
  }
  hipMemsetAsync(cnt_n, 0, 3 * NG * sizeof(float), stream);
  k_count<<<512, 256, 0, stream>>>(node_batch, N, cnt_n);
  k_count<<<512, 256, 0, stream>>>(edge_batch, E, cnt_e);
  k_count<<<512, 256, 0, stream>>>(angle_batch, A, cnt_a);

  const float* x_cur = x0;
  const float* e_cur = e0;
  const float* a_cur = a0;

  for (int i = 0; i < 2; ++i) {
    // 1. node-pair -> edge update + graph norm
    k_mm_edge<<<(E / 16 + 3) / 4, 256, 0, stream>>>(x_cur, e_cur, e_buf, edge_index,
                                                    wt_ne + (size_t)i * 320 * 64, b_ne + i * 64, E);
    hipMemsetAsync(s1, 0, 2 * NG * sizeof(float), stream);
    k_stats<<<2048, 256, 0, stream>>>(e_buf, nullptr, e_buf, edge_batch, (long)E * 64, 6, s1, s2);
    k_gnorm<<<2048, 256, 0, stream>>>(e_buf, edge_batch, (long)E * 64, 6, s1, s2, cnt_e,
                                      g_e + i * 64, be_e + i * 64);
    // 2. edge-pair -> angle update + graph norm
    k_mm_angle<<<(A / 16 + 3) / 4, 256, 0, stream>>>(e_buf, a_cur, a_buf, tb_index,
                                                     wt_ea + (size_t)i * 192 * 64, b_ea + i * 64, A);
    hipMemsetAsync(s1, 0, 2 * NG * sizeof(float), stream);
    k_stats<<<2048, 256, 0, stream>>>(a_buf, nullptr, a_buf, angle_batch, (long)A * 64, 6, s1, s2);
    k_gnorm<<<2048, 256, 0, stream>>>(a_buf, angle_batch, (long)A * 64, 6, s1, s2, cnt_a,
                                      g_a + i * 64, be_a + i * 64);
    // 3. edge_graph_mp (scatter to edges) + add + graph norm
    hipMemsetAsync(agg, 0, (size_t)E * 64 * sizeof(float), stream);
    k_mm_emp<<<(A / 16 + 3) / 4, 256, 0, stream>>>(e_buf, a_buf, tb_index,
                                                   wt_emp + (size_t)i * 192 * 64, b_emp + i * 64, agg, A);
    hipMemsetAsync(s1, 0, 2 * NG * sizeof(float), stream);
    k_stats<<<2048, 256, 0, stream>>>(e_buf, agg, e_buf, edge_batch, (long)E * 64, 6, s1, s2);
    k_gnorm<<<2048, 256, 0, stream>>>(e_buf, edge_batch, (long)E * 64, 6, s1, s2, cnt_e,
                                      g_emp + i * 64, be_emp + i * 64);
    // 4. node_graph_mp (scatter to nodes) + add + graph norm
    hipMemsetAsync(agg, 0, (size_t)N * 128 * sizeof(float), stream);
    k_mm_nmp<<<(E / 16 + 3) / 4, 256, 0, stream>>>(x_cur, e_buf, edge_index,
                                                   wt_nmp + (size_t)i * 320 * 128, b_nmp + i * 128, agg, E);
    hipMemsetAsync(s1, 0, 2 * NG * sizeof(float), stream);
    k_stats<<<2048, 256, 0, stream>>>(x_cur, agg, x_out, node_batch, (long)N * 128, 7, s1, s2);
    k_gnorm<<<2048, 256, 0, stream>>>(x_out, node_batch, (long)N * 128, 7, s1, s2, cnt_n,
                                      g_nmp + i * 128, be_nmp + i * 128);

    x_cur = x_out; e_cur = e_buf; a_cur = a_buf;
  }
}

// Round 3
// 2109.345 us; speedup vs baseline: 1.3048x; 1.3048x over previous
//
#include <hip/hip_runtime.h>

typedef __attribute__((ext_vector_type(8))) short bf16x8_t;
typedef __attribute__((ext_vector_type(4))) float f32x4_t;

constexpr int NG = 16;
constexpr float EPS = 1e-5f;

__device__ inline unsigned short f2bf(float f) {
  unsigned u = __builtin_bit_cast(unsigned, f);
  u += 0x7FFFu + ((u >> 16) & 1u);
  return (unsigned short)(u >> 16);
}
__device__ inline float bf2f(unsigned short u) {
  unsigned x = ((unsigned)u) << 16;
  return __builtin_bit_cast(float, x);
}

// =====================================================================
// EDGE update MM: e1_raw = affine(e_in) + [x_s|x_d|affine(e_in)]@W + bias
// fused per-graph stats of output. e_in/e_out may alias (in-place, wave
// only touches its own 16 rows).
// =====================================================================
__global__ __launch_bounds__(256) void k_mm_edge(
    const float* __restrict__ x, const float* e_in, float* e_out,
    const int* __restrict__ ei, const int* __restrict__ ebatch,
    const unsigned short* __restrict__ Wt, const float* __restrict__ bias,
    const float* __restrict__ afA, const float* __restrict__ afB,
    float* __restrict__ gs1, float* __restrict__ gs2, int nE)
{
  __shared__ float lA[1024], lB[1024];
  __shared__ float ls1[NG], ls2[NG];
  for (int i = threadIdx.x; i < 1024; i += 256) { lA[i] = afA[i]; lB[i] = afB[i]; }
  if (threadIdx.x < NG) { ls1[threadIdx.x] = 0.f; ls2[threadIdx.x] = 0.f; }
  __syncthreads();
  int gw = (int)((blockIdx.x * 256u + threadIdx.x) >> 6);
  int ntile = nE >> 4;
  bool act = gw < ntile;
  int lane = threadIdx.x & 63;
  int colb = lane & 15;
  int ko = (lane >> 4) << 3;
  int rowb = (lane >> 4) << 2;
  float sr[4] = {0.f,0.f,0.f,0.f}, ssr[4] = {0.f,0.f,0.f,0.f};
  if (act) {
    int row = (gw << 4) + colb;
    int s = ei[row], d = ei[nE + row];
    int ge = ebatch[row];
    const float* xs = x + (size_t)s * 128;
    const float* xd = x + (size_t)d * 128;
    const float* er = e_in + (size_t)row * 64;
    f32x4_t acc[4] = {};
#pragma unroll
    for (int c = 0; c < 10; ++c) {
      float v[8];
      if (c < 8) {
        const float* bp = (c < 4) ? xs + c * 32 : xd + (c - 4) * 32;
        float4 f0 = *(const float4*)(bp + ko);
        float4 f1 = *(const float4*)(bp + ko + 4);
        v[0]=f0.x; v[1]=f0.y; v[2]=f0.z; v[3]=f0.w;
        v[4]=f1.x; v[5]=f1.y; v[6]=f1.z; v[7]=f1.w;
      } else {
        int fb = (c - 8) * 32 + ko;
        float4 f0 = *(const float4*)(er + fb);
        float4 f1 = *(const float4*)(er + fb + 4);
        float vv[8] = {f0.x,f0.y,f0.z,f0.w,f1.x,f1.y,f1.z,f1.w};
#pragma unroll
        for (int k = 0; k < 8; ++k) v[k] = vv[k] * lA[ge*64 + fb + k] + lB[ge*64 + fb + k];
      }
      bf16x8_t a;
#pragma unroll
      for (int k = 0; k < 8; ++k) a[k] = (short)f2bf(v[k]);
#pragma unroll
      for (int nb = 0; nb < 4; ++nb) {
        bf16x8_t b = *(const bf16x8_t*)(Wt + (size_t)(nb * 16 + colb) * 320 + c * 32 + ko);
        acc[nb] = __builtin_amdgcn_mfma_f32_16x16x32_bf16(a, b, acc[nb], 0, 0, 0);
      }
    }
#pragma unroll
    for (int r = 0; r < 4; ++r) {
      int e_ = (gw << 4) + rowb + r;
      int gr = ebatch[e_];
#pragma unroll
      for (int nb = 0; nb < 4; ++nb) {
        int col = nb * 16 + colb;
        size_t off = (size_t)e_ * 64 + col;
        float vv = e_in[off] * lA[gr*64 + col] + lB[gr*64 + col] + bias[col] + acc[nb][r];
        e_out[off] = vv;
        sr[r] += vv; ssr[r] += vv * vv;
      }
    }
  }
#pragma unroll
  for (int m = 1; m <= 8; m <<= 1)
#pragma unroll
    for (int r = 0; r < 4; ++r) { sr[r] += __shfl_xor(sr[r], m); ssr[r] += __shfl_xor(ssr[r], m); }
  if (act && colb == 0) {
#pragma unroll
    for (int r = 0; r < 4; ++r) {
      int g = ebatch[(gw << 4) + rowb + r];
      atomicAdd(&ls1[g], sr[r]); atomicAdd(&ls2[g], ssr[r]);
    }
  }
  __syncthreads();
  if (threadIdx.x < NG) {
    atomicAdd(&gs1[threadIdx.x], ls1[threadIdx.x]);
    atomicAdd(&gs2[threadIdx.x], ls2[threadIdx.x]);
  }
}

// =====================================================================
// ANGLE update MM: a1 = affA(a_in) + [affE(e_s)|affE(e_d)|affA(a_in)]@W + b
// fused stats. a_in/a_out may alias.
// =====================================================================
__global__ __launch_bounds__(256) void k_mm_angle(
    const float* __restrict__ e, const float* a_in, float* a_out,
    const int* __restrict__ ti, const int* __restrict__ ebatch,
    const int* __restrict__ abatch,
    const unsigned short* __restrict__ Wt, const float* __restrict__ bias,
    const float* __restrict__ afEA, const float* __restrict__ afEB,
    const float* __restrict__ afAA, const float* __restrict__ afAB,
    float* __restrict__ gs1, float* __restrict__ gs2, int nA)
{
  __shared__ float lEA[1024], lEB[1024], lAA[1024], lAB[1024];
  __shared__ float ls1[NG], ls2[NG];
  for (int i = threadIdx.x; i < 1024; i += 256) {
    lEA[i] = afEA[i]; lEB[i] = afEB[i]; lAA[i] = afAA[i]; lAB[i] = afAB[i];
  }
  if (threadIdx.x < NG) { ls1[threadIdx.x] = 0.f; ls2[threadIdx.x] = 0.f; }
  __syncthreads();
  int gw = (int)((blockIdx.x * 256u + threadIdx.x) >> 6);
  int ntile = nA >> 4;
  bool act = gw < ntile;
  int lane = threadIdx.x & 63;
  int colb = lane & 15;
  int ko = (lane >> 4) << 3;
  int rowb = (lane >> 4) << 2;
  float sr[4] = {0.f,0.f,0.f,0.f}, ssr[4] = {0.f,0.f,0.f,0.f};
  if (act) {
    int row = (gw << 4) + colb;
    int s = ti[row], d = ti[nA + row];
    int gs = ebatch[s], gd = ebatch[d], ga = abatch[row];
    const float* es = e + (size_t)s * 64;
    const float* ed = e + (size_t)d * 64;
    const float* ar = a_in + (size_t)row * 64;
    f32x4_t acc[4] = {};
#pragma unroll
    for (int c = 0; c < 6; ++c) {
      const float* bp; const float* tA; const float* tB; int fb;
      if (c < 2)      { bp = es + c * 32;       fb = c * 32 + ko;       tA = lEA + gs*64; tB = lEB + gs*64; }
      else if (c < 4) { bp = ed + (c - 2) * 32; fb = (c - 2) * 32 + ko; tA = lEA + gd*64; tB = lEB + gd*64; }
      else            { bp = ar + (c - 4) * 32; fb = (c - 4) * 32 + ko; tA = lAA + ga*64; tB = lAB + ga*64; }
      float4 f0 = *(const float4*)(bp + ko);
      float4 f1 = *(const float4*)(bp + ko + 4);
      float vv[8] = {f0.x,f0.y,f0.z,f0.w,f1.x,f1.y,f1.z,f1.w};
      bf16x8_t a;
#pragma unroll
      for (int k = 0; k < 8; ++k) a[k] = (short)f2bf(vv[k] * tA[fb + k] + tB[fb + k]);
#pragma unroll
      for (int nb = 0; nb < 4; ++nb) {
        bf16x8_t b = *(const bf16x8_t*)(Wt + (size_t)(nb * 16 + colb) * 192 + c * 32 + ko);
        acc[nb] = __builtin_amdgcn_mfma_f32_16x16x32_bf16(a, b, acc[nb], 0, 0, 0);
      }
    }
#pragma unroll
    for (int r = 0; r < 4; ++r) {
      int a_ = (gw << 4) + rowb + r;
      int gr = abatch[a_];
#pragma unroll
      for (int nb = 0; nb < 4; ++nb) {
        int col = nb * 16 + colb;
        size_t off = (size_t)a_ * 64 + col;
        float vv = a_in[off] * lAA[gr*64 + col] + lAB[gr*64 + col] + bias[col] + acc[nb][r];
        a_out[off] = vv;
        sr[r] += vv; ssr[r] += vv * vv;
      }
    }
  }
#pragma unroll
  for (int m = 1; m <= 8; m <<= 1)
#pragma unroll
    for (int r = 0; r < 4; ++r) { sr[r] += __shfl_xor(sr[r], m); ssr[r] += __shfl_xor(ssr[r], m); }
  if (act && colb == 0) {
#pragma unroll
    for (int r = 0; r < 4; ++r) {
      int g = abatch[(gw << 4) + rowb + r];
      atomicAdd(&ls1[g], sr[r]); atomicAdd(&ls2[g], ssr[r]);
    }
  }
  __syncthreads();
  if (threadIdx.x < NG) {
    atomicAdd(&gs1[threadIdx.x], ls1[threadIdx.x]);
    atomicAdd(&gs2[threadIdx.x], ls2[threadIdx.x]);
  }
}

// =====================================================================
// edge_graph_mp message MM: msg = relu([affE(e_s)|affE(e_d)|affA(a)]@W + b)
// -> bf16 msg[A][64], NO atomics.
// =====================================================================
__global__ __launch_bounds__(256) void k_mm_emp(
    const float* __restrict__ e, const float* __restrict__ a_,
    const int* __restrict__ ti, const int* __restrict__ ebatch,
    const int* __restrict__ abatch,
    const unsigned short* __restrict__ Wt, const float* __restrict__ bias,
    const float* __restrict__ afEA, const float* __restrict__ afEB,
    const float* __restrict__ afAA, const float* __restrict__ afAB,
    unsigned short* __restrict__ msg, int nA)
{
  __shared__ float lEA[1024], lEB[1024], lAA[1024], lAB[1024];
  for (int i = threadIdx.x; i < 1024; i += 256) {
    lEA[i] = afEA[i]; lEB[i] = afEB[i]; lAA[i] = afAA[i]; lAB[i] = afAB[i];
  }
  __syncthreads();
  int gw = (int)((blockIdx.x * 256u + threadIdx.x) >> 6);
  int ntile = nA >> 4;
  if (gw >= ntile) return;
  int lane = threadIdx.x & 63;
  int colb = lane & 15;
  int ko = (lane >> 4) << 3;
  int rowb = (lane >> 4) << 2;
  int row = (gw << 4) + colb;
  int s = ti[row], d = ti[nA + row];
  int gs = ebatch[s], gd = ebatch[d], ga = abatch[row];
  const float* es = e + (size_t)s * 64;
  const float* ed = e + (size_t)d * 64;
  const float* ar = a_ + (size_t)row * 64;
  f32x4_t acc[4] = {};
#pragma unroll
  for (int c = 0; c < 6; ++c) {
    const float* bp; const float* tA; const float* tB; int fb;
    if (c < 2)      { bp = es + c * 32;       fb = c * 32 + ko;       tA = lEA + gs*64; tB = lEB + gs*64; }
    else if (c < 4) { bp = ed + (c - 2) * 32; fb = (c - 2) * 32 + ko; tA = lEA + gd*64; tB = lEB + gd*64; }
    else            { bp = ar + (c - 4) * 32; fb = (c - 4) * 32 + ko; tA = lAA + ga*64; tB = lAB + ga*64; }
    float4 f0 = *(const float4*)(bp + ko);
    float4 f1 = *(const float4*)(bp + ko + 4);
    float vv[8] = {f0.x,f0.y,f0.z,f0.w,f1.x,f1.y,f1.z,f1.w};
    bf16x8_t a;
#pragma unroll
    for (int k = 0; k < 8; ++k) a[k] = (short)f2bf(vv[k] * tA[fb + k] + tB[fb + k]);
#pragma unroll
    for (int nb = 0; nb < 4; ++nb) {
      bf16x8_t b = *(const bf16x8_t*)(Wt + (size_t)(nb * 16 + colb) * 192 + c * 32 + ko);
      acc[nb] = __builtin_amdgcn_mfma_f32_16x16x32_bf16(a, b, acc[nb], 0, 0, 0);
    }
  }
#pragma unroll
  for (int r = 0; r < 4; ++r) {
    int a_idx = (gw << 4) + rowb + r;
#pragma unroll
    for (int nb = 0; nb < 4; ++nb) {
      int col = nb * 16 + colb;
      float v = fmaxf(acc[nb][r] + bias[col], 0.f);
      msg[(size_t)a_idx * 64 + col] = f2bf(v);
    }
  }
}

// =====================================================================
// node_graph_mp message MM: msg = relu([x_s|x_d|affE(e)]@W + b) -> bf16 msg[E][128]
// =====================================================================
__global__ __launch_bounds__(256) void k_mm_nmp(
    const float* __restrict__ x, const float* __restrict__ e,
    const int* __restrict__ ei, const int* __restrict__ ebatch,
    const unsigned short* __restrict__ Wt, const float* __restrict__ bias,
    const float* __restrict__ afEA, const float* __restrict__ afEB,
    unsigned short* __restrict__ msg, int nE)
{
  __shared__ float lA[1024], lB[1024];
  for (int i = threadIdx.x; i < 1024; i += 256) { lA[i] = afEA[i]; lB[i] = afEB[i]; }
  __syncthreads();
  int gw = (int)((blockIdx.x * 256u + threadIdx.x) >> 6);
  int ntile = nE >> 4;
  if (gw >= ntile) return;
  int lane = threadIdx.x & 63;
  int colb = lane & 15;
  int ko = (lane >> 4) << 3;
  int rowb = (lane >> 4) << 2;
  int row = (gw << 4) + colb;
  int s = ei[row], d = ei[nE + row];
  int ge = ebatch[row];
  const float* xs = x + (size_t)s * 128;
  const float* xd = x + (size_t)d * 128;
  const float* er = e + (size_t)row * 64;
  f32x4_t acc[8] = {};
#pragma unroll
  for (int c = 0; c < 10; ++c) {
    float v[8];
    if (c < 8) {
      const float* bp = (c < 4) ? xs + c * 32 : xd + (c - 4) * 32;
      float4 f0 = *(const float4*)(bp + ko);
      float4 f1 = *(const float4*)(bp + ko + 4);
      v[0]=f0.x; v[1]=f0.y; v[2]=f0.z; v[3]=f0.w;
      v[4]=f1.x; v[5]=f1.y; v[6]=f1.z; v[7]=f1.w;
    } else {
      int fb = (c - 8) * 32 + ko;
      float4 f0 = *(const float4*)(er + fb);
      float4 f1 = *(const float4*)(er + fb + 4);
      float vv[8] = {f0.x,f0.y,f0.z,f0.w,f1.x,f1.y,f1.z,f1.w};
#pragma unroll
      for (int k = 0; k < 8; ++k) v[k] = vv[k] * lA[ge*64 + fb + k] + lB[ge*64 + fb + k];
    }
    bf16x8_t a;
#pragma unroll
    for (int k = 0; k < 8; ++k) a[k] = (short)f2bf(v[k]);
#pragma unroll
    for (int nb = 0; nb < 8; ++nb) {
      bf16x8_t b = *(const bf16x8_t*)(Wt + (size_t)(nb * 16 + colb) * 320 + c * 32 + ko);
      acc[nb] = __builtin_amdgcn_mfma_f32_16x16x32_bf16(a, b, acc[nb], 0, 0, 0);
    }
  }
#pragma unroll
  for (int r = 0; r < 4; ++r) {
    int e_ = (gw << 4) + rowb + r;
#pragma unroll
    for (int nb = 0; nb < 8; ++nb) {
      int col = nb * 16 + colb;
      float v = fmaxf(acc[nb][r] + bias[col], 0.f);
      msg[(size_t)e_ * 128 + col] = f2bf(v);
    }
  }
}

// =====================================================================
// CSR gather-reduce over edges: e2 = affE1(e1) + sum(msg rows); fused stats.
// One wave per destination edge; lane = col. e_in/e_out may alias.
// =====================================================================
__global__ __launch_bounds__(256) void k_red_e(
    const unsigned short* __restrict__ msg, const float* e_in, float* e_out,
    const int* __restrict__ ptr, const int* __restrict__ perm,
    const int* __restrict__ ebatch,
    const float* __restrict__ afA, const float* __restrict__ afB,
    float* __restrict__ gs1, float* __restrict__ gs2, int nE)
{
  __shared__ float lA[1024], lB[1024], ls1[NG], ls2[NG];
  for (int i = threadIdx.x; i < 1024; i += 256) { lA[i] = afA[i]; lB[i] = afB[i]; }
  if (threadIdx.x < NG) { ls1[threadIdx.x] = 0.f; ls2[threadIdx.x] = 0.f; }
  __syncthreads();
  int lane = threadIdx.x & 63;
  int wv = (int)((blockIdx.x * 256u + threadIdx.x) >> 6);
  int nw = (int)((gridDim.x * 256u) >> 6);
  for (int eidx = wv; eidx < nE; eidx += nw) {
    int p0 = ptr[eidx], p1 = ptr[eidx + 1];
    float sum = 0.f;
    for (int j = p0; j < p1; ++j) {
      int aidx = perm[j];
      sum += bf2f(msg[(size_t)aidx * 64 + lane]);
    }
    int g = ebatch[eidx];
    size_t off = (size_t)eidx * 64 + lane;
    float v = e_in[off] * lA[g*64 + lane] + lB[g*64 + lane] + sum;
    e_out[off] = v;
    float s = v, ss = v * v;
#pragma unroll
    for (int m = 1; m < 64; m <<= 1) { s += __shfl_xor(s, m); ss += __shfl_xor(ss, m); }
    if (lane == 0) { atomicAdd(&ls1[g], s); atomicAdd(&ls2[g], ss); }
  }
  __syncthreads();
  if (threadIdx.x < NG) {
    atomicAdd(&gs1[threadIdx.x], ls1[threadIdx.x]);
    atomicAdd(&gs2[threadIdx.x], ls2[threadIdx.x]);
  }
}

// =====================================================================
// CSR gather-reduce over nodes: h = x + sum(msg rows); fused stats.
// One wave per node; lane handles 2 cols. x_in/out may alias.
// =====================================================================
__global__ __launch_bounds__(256) void k_red_n(
    const unsigned short* __restrict__ msg, const float* x_in, float* out,
    const int* __restrict__ ptr, const int* __restrict__ perm,
    const int* __restrict__ nbatch,
    float* __restrict__ gs1, float* __restrict__ gs2, int nN)
{
  __shared__ float ls1[NG], ls2[NG];
  if (threadIdx.x < NG) { ls1[threadIdx.x] = 0.f; ls2[threadIdx.x] = 0.f; }
  __syncthreads();
  int lane = threadIdx.x & 63;
  int wv = (int)((blockIdx.x * 256u + threadIdx.x) >> 6);
  int nw = (int)((gridDim.x * 256u) >> 6);
  for (int n = wv; n < nN; n += nw) {
    int p0 = ptr[n], p1 = ptr[n + 1];
    float s0 = 0.f, s1v = 0.f;
    for (int j = p0; j < p1; ++j) {
      int e = perm[j];
      unsigned u = *(const unsigned*)(msg + (size_t)e * 128 + lane * 2);
      s0 += bf2f((unsigned short)(u & 0xffffu));
      s1v += bf2f((unsigned short)(u >> 16));
    }
    size_t off = (size_t)n * 128 + lane * 2;
    float h0 = x_in[off] + s0, h1 = x_in[off + 1] + s1v;
    out[off] = h0; out[off + 1] = h1;
    float s = h0 + h1, ss = h0 * h0 + h1 * h1;
#pragma unroll
    for (int m = 1; m < 64; m <<= 1) { s += __shfl_xor(s, m); ss += __shfl_xor(ss, m); }
    if (lane == 0) { int g = nbatch[n]; atomicAdd(&ls1[g], s); atomicAdd(&ls2[g], ss); }
  }
  __syncthreads();
  if (threadIdx.x < NG) {
    atomicAdd(&gs1[threadIdx.x], ls1[threadIdx.x]);
    atomicAdd(&gs2[threadIdx.x], ls2[threadIdx.x]);
  }
}

// ---- affine table construction: A=inv*w[f], B=b[f]-m*inv*w[f] ----
__global__ __launch_bounds__(256) void k_mkaff(
    const float* __restrict__ s1, const float* __restrict__ s2,
    const float* __restrict__ cnt, int F,
    const float* __restrict__ w, const float* __restrict__ b,
    float* __restrict__ A, float* __restrict__ B)
{
  int idx = blockIdx.x * 256 + threadIdx.x;
  if (idx >= NG * F) return;
  int g = idx / F, f = idx - g * F;
  float norm = fmaxf(cnt[g], 1.f) * (float)F;
  float m = s1[g] / norm;
  float var = s2[g] / norm - m * m;
  float inv = rsqrtf(var + EPS);
  float a = inv * w[f];
  A[idx] = a;
  B[idx] = b[f] - m * a;
}

__global__ __launch_bounds__(256) void k_idaff(float* __restrict__ A, float* __restrict__ B, int n)
{
  int idx = blockIdx.x * 256 + threadIdx.x;
  if (idx < n) { A[idx] = 1.f; B[idx] = 0.f; }
}

// ---- apply materialized norm to x (in-place) ----
__global__ __launch_bounds__(256) void k_apply(
    float* h, const int* __restrict__ batch,
    const float* __restrict__ A, const float* __restrict__ B, long total)
{
  long stride = (long)gridDim.x * 256;
  for (long idx = (long)blockIdx.x * 256 + threadIdx.x; idx < total; idx += stride) {
    int g = batch[idx >> 7];
    int f = (int)(idx & 127);
    h[idx] = h[idx] * A[(g << 7) | f] + B[(g << 7) | f];
  }
}

__global__ __launch_bounds__(256) void k_count(
    const int* __restrict__ batch, int n, float* __restrict__ cnt)
{
  __shared__ float lc[NG];
  if (threadIdx.x < NG) lc[threadIdx.x] = 0.f;
  __syncthreads();
  for (int i = blockIdx.x * 256 + threadIdx.x; i < n; i += gridDim.x * 256)
    atomicAdd(&lc[batch[i]], 1.f);
  __syncthreads();
  if (threadIdx.x < NG) atomicAdd(&cnt[threadIdx.x], lc[threadIdx.x]);
}

// ---- CSR build: histogram, 3-kernel scan, scatter ----
__global__ __launch_bounds__(256) void k_hist(
    const int* __restrict__ dst, int n, int* __restrict__ cnt)
{
  for (int i = blockIdx.x * 256 + threadIdx.x; i < n; i += gridDim.x * 256)
    atomicAdd(&cnt[dst[i]], 1);
}

__global__ __launch_bounds__(256) void k_scan1(
    const int* __restrict__ in, int* __restrict__ out, int* __restrict__ bsum, int n)
{
  __shared__ int wtot[4];
  int tid = threadIdx.x, lane = tid & 63, wid = tid >> 6;
  int base = blockIdx.x * 1024 + tid * 4;
  int v[4];
#pragma unroll
  for (int k = 0; k < 4; ++k) v[k] = (base + k < n) ? in[base + k] : 0;
  int tsum = v[0] + v[1] + v[2] + v[3];
  int incl = tsum;
#pragma unroll
  for (int off = 1; off < 64; off <<= 1) {
    int up = __shfl_up(incl, off);
    if (lane >= off) incl += up;
  }
  if (lane == 63) wtot[wid] = incl;
  __syncthreads();
  if (tid == 0) {
    int r = 0;
#pragma unroll
    for (int w2 = 0; w2 < 4; ++w2) { int t = wtot[w2]; wtot[w2] = r; r += t; }
    bsum[blockIdx.x] = r;
  }
  __syncthreads();
  int excl = wtot[wid] + incl - tsum;
#pragma unroll
  for (int k = 0; k < 4; ++k) {
    if (base + k < n) out[base + k] = excl;
    excl += v[k];
  }
}

__global__ __launch_bounds__(256) void k_scan2(int* __restrict__ bsum, int nb, int* __restrict__ total_out)
{
  __shared__ int wtot[4];
  int tid = threadIdx.x, lane = tid & 63, wid = tid >> 6;
  int base = tid * 4;
  int v[4];
#pragma unroll
  for (int k = 0; k < 4; ++k) v[k] = (base + k < nb) ? bsum[base + k] : 0;
  int tsum = v[0] + v[1] + v[2] + v[3];
  int incl = tsum;
#pragma unroll
  for (int off = 1; off < 64; off <<= 1) {
    int up = __shfl_up(incl, off);
    if (lane >= off) incl += up;
  }
  if (lane == 63) wtot[wid] = incl;
  __syncthreads();
  if (tid == 0) {
    int r = 0;
#pragma unroll
    for (int w2 = 0; w2 < 4; ++w2) { int t = wtot[w2]; wtot[w2] = r; r += t; }
    *total_out = r;
  }
  __syncthreads();
  int excl = wtot[wid] + incl - tsum;
#pragma unroll
  for (int k = 0; k < 4; ++k) {
    if (base + k < nb) bsum[base + k] = excl;
    excl += v[k];
  }
}

__global__ __launch_bounds__(256) void k_scan3(
    int* __restrict__ ptr, int* __restrict__ cur, const int* __restrict__ bsum, int n)
{
  for (int i = blockIdx.x * 256 + threadIdx.x; i < n; i += gridDim.x * 256) {
    int v = ptr[i] + bsum[i >> 10];
    ptr[i] = v; cur[i] = v;
  }
}

__global__ __launch_bounds__(256) void k_scatter(
    const int* __restrict__ dst, int* __restrict__ cur, int* __restrict__ perm, int n)
{
  for (int i = blockIdx.x * 256 + threadIdx.x; i < n; i += gridDim.x * 256) {
    int d = dst[i];
    int p = atomicAdd(&cur[d], 1);
    perm[p] = i;
  }
}

// ---- weight prep: W[k][j] fp32 -> Wt[j][k] bf16 ----
__global__ __launch_bounds__(256) void k_wt(
    const float* __restrict__ W, unsigned short* __restrict__ Wt, int K, int NO)
{
  int idx = blockIdx.x * 256 + threadIdx.x;
  if (idx >= K * NO) return;
  int k = idx / NO, j = idx - k * NO;
  Wt[(size_t)j * K + k] = f2bf(W[idx]);
}

extern "C" void kernel_launch(void* const* d_in, const int* in_sizes, int n_in,
                              void* d_out, int out_size, void* d_ws, size_t ws_size,
                              hipStream_t stream)
{
  const float* x0    = (const float*)d_in[0];
  const float* e0    = (const float*)d_in[1];
  const float* a0    = (const float*)d_in[2];
  const float* W_ne  = (const float*)d_in[3];
  const float* b_ne  = (const float*)d_in[4];
  const float* g_e   = (const float*)d_in[5];
  const float* be_e  = (const float*)d_in[6];
  const float* W_ea  = (const float*)d_in[7];
  const float* b_ea  = (const float*)d_in[8];
  const float* g_a   = (const float*)d_in[9];
  const float* be_a  = (const float*)d_in[10];
  const float* W_emp = (const float*)d_in[11];
  const float* b_emp = (const float*)d_in[12];
  const float* g_emp = (const float*)d_in[13];
  const float* be_emp= (const float*)d_in[14];
  const float* W_nmp = (const float*)d_in[15];
  const float* b_nmp = (const float*)d_in[16];
  const float* g_nmp = (const float*)d_in[17];
  const float* be_nmp= (const float*)d_in[18];
  const int* node_batch  = (const int*)d_in[19];
  const int* edge_index  = (const int*)d_in[20];
  const int* edge_batch  = (const int*)d_in[21];
  const int* tb_index    = (const int*)d_in[22];
  const int* angle_batch = (const int*)d_in[23];

  const int N = in_sizes[0] / 128;
  const int E = in_sizes[1] / 64;
  const int A = in_sizes[2] / 64;

  // ---- workspace layout (bytes, 256-aligned) ----
  char* wsp = (char*)d_ws;
  auto alloc = [&](size_t bytes) { char* p = wsp; wsp += (bytes + 255) & ~(size_t)255; return p; };
  float*          eA     = (float*)alloc((size_t)E * 64 * 4);
  float*          aA     = (float*)alloc((size_t)A * 64 * 4);
  unsigned short* msg    = (unsigned short*)alloc((size_t)A * 64 * 2);  // == E*128*2
  int* ptr_n  = (int*)alloc((size_t)(N + 1) * 4);
  int* cur_n  = (int*)alloc((size_t)N * 4);
  int* perm_n = (int*)alloc((size_t)E * 4);
  int* ptr_e  = (int*)alloc((size_t)(E + 1) * 4);
  int* cur_e  = (int*)alloc((size_t)E * 4);
  int* perm_e = (int*)alloc((size_t)A * 4);
  int* bsum   = (int*)alloc(4096 * 4);
  // stats: ONE contiguous block so the memsets actually cover s2/cnt_*
  // (round-2 bug: alloc() pads to 256B, so s1+NG != s2 -> s2 was never zeroed)
  float* stats = (float*)alloc(5 * NG * 4);
  float* s1    = stats;
  float* s2    = stats + NG;
  float* cnt_n = stats + 2 * NG;
  float* cnt_e = stats + 3 * NG;
  float* cnt_a = stats + 4 * NG;
  float* afE_idA = (float*)alloc(1024 * 4); float* afE_idB = (float*)alloc(1024 * 4);
  float* afA_idA = (float*)alloc(1024 * 4); float* afA_idB = (float*)alloc(1024 * 4);
  float* afE1A   = (float*)alloc(1024 * 4); float* afE1B   = (float*)alloc(1024 * 4);
  float* afE2A   = (float*)alloc(1024 * 4); float* afE2B   = (float*)alloc(1024 * 4);
  float* afA1A   = (float*)alloc(1024 * 4); float* afA1B   = (float*)alloc(1024 * 4);
  float* afXA    = (float*)alloc(2048 * 4); float* afXB    = (float*)alloc(2048 * 4);
  unsigned short* wt_ne  = (unsigned short*)alloc((size_t)2 * 320 * 64 * 2);
  unsigned short* wt_ea  = (unsigned short*)alloc((size_t)2 * 192 * 64 * 2);
  unsigned short* wt_emp = (unsigned short*)alloc((size_t)2 * 192 * 64 * 2);
  unsigned short* wt_nmp = (unsigned short*)alloc((size_t)2 * 320 * 128 * 2);

  float* x_out = (float*)d_out;

  // ---- one-time prep ----
  for (int i = 0; i < 2; ++i) {
    k_wt<<<(320*64 + 255)/256, 256, 0, stream>>>(W_ne  + (size_t)i*320*64,  wt_ne  + (size_t)i*320*64,  320, 64);
    k_wt<<<(192*64 + 255)/256, 256, 0, stream>>>(W_ea  + (size_t)i*192*64,  wt_ea  + (size_t)i*192*64,  192, 64);
    k_wt<<<(192*64 + 255)/256, 256, 0, stream>>>(W_emp + (size_t)i*192*64,  wt_emp + (size_t)i*192*64,  192, 64);
    k_wt<<<(320*128 + 255)/256, 256, 0, stream>>>(W_nmp + (size_t)i*320*128, wt_nmp + (size_t)i*320*128, 320, 128);
  }
  hipMemsetAsync(stats, 0, 5 * NG * 4, stream);  // zero s1,s2,cnt_n,cnt_e,cnt_a
  k_count<<<512, 256, 0, stream>>>(node_batch, N, cnt_n);
  k_count<<<512, 256, 0, stream>>>(edge_batch, E, cnt_e);
  k_count<<<512, 256, 0, stream>>>(angle_batch, A, cnt_a);
  k_idaff<<<4, 256, 0, stream>>>(afE_idA, afE_idB, 1024);
  k_idaff<<<4, 256, 0, stream>>>(afA_idA, afA_idB, 1024);

  // CSR over nodes (dst of edge_index) and over edges (dst of threebody)
  hipMemsetAsync(cur_n, 0, (size_t)N * 4, stream);
  hipMemsetAsync(cur_e, 0, (size_t)E * 4, stream);
  k_hist<<<1024, 256, 0, stream>>>(edge_index + E, E, cur_n);
  k_hist<<<1024, 256, 0, stream>>>(tb_index + A, A, cur_e);
  int nbN = (N + 1023) / 1024, nbE = (E + 1023) / 1024;
  k_scan1<<<nbN, 256, 0, stream>>>(cur_n, ptr_n, bsum, N);
  k_scan2<<<1, 256, 0, stream>>>(bsum, nbN, ptr_n + N);
  k_scan3<<<1024, 256, 0, stream>>>(ptr_n, cur_n, bsum, N);
  k_scatter<<<1024, 256, 0, stream>>>(edge_index + E, cur_n, perm_n, E);
  k_scan1<<<nbE, 256, 0, stream>>>(cur_e, ptr_e, bsum, E);
  k_scan2<<<1, 256, 0, stream>>>(bsum, nbE, ptr_e + E);
  k_scan3<<<1024, 256, 0, stream>>>(ptr_e, cur_e, bsum, E);
  k_scatter<<<1024, 256, 0, stream>>>(tb_index + A, cur_e, perm_e, A);

  const float* x_cur = x0;
  int blkE = (E / 16 + 3) / 4;   // 4 waves/block
  int blkA = (A / 16 + 3) / 4;

  for (int i = 0; i < 2; ++i) {
    const float* e_in  = (i == 0) ? e0 : eA;
    const float* a_in  = (i == 0) ? a0 : aA;
    const float* fEinA = (i == 0) ? afE_idA : afE2A;
    const float* fEinB = (i == 0) ? afE_idB : afE2B;
    const float* fAinA = (i == 0) ? afA_idA : afA1A;
    const float* fAinB = (i == 0) ? afA_idB : afA1B;

    // 1. edge update (+ fused stats) -> affE1
    hipMemsetAsync(s1, 0, 2 * NG * 4, stream);
    k_mm_edge<<<blkE, 256, 0, stream>>>(x_cur, e_in, eA, edge_index, edge_batch,
                                        wt_ne + (size_t)i*320*64, b_ne + i*64,
                                        fEinA, fEinB, s1, s2, E);
    k_mkaff<<<4, 256, 0, stream>>>(s1, s2, cnt_e, 64, g_e + i*64, be_e + i*64, afE1A, afE1B);

    // 2. angle update (+ fused stats) -> affA1
    hipMemsetAsync(s1, 0, 2 * NG * 4, stream);
    k_mm_angle<<<blkA, 256, 0, stream>>>(eA, a_in, aA, tb_index, edge_batch, angle_batch,
                                         wt_ea + (size_t)i*192*64, b_ea + i*64,
                                         afE1A, afE1B, fAinA, fAinB, s1, s2, A);
    k_mkaff<<<4, 256, 0, stream>>>(s1, s2, cnt_a, 64, g_a + i*64, be_a + i*64, afA1A, afA1B);

    // 3. edge_graph_mp: messages -> bf16 msg, then CSR reduce (+stats) -> affE2
    k_mm_emp<<<blkA, 256, 0, stream>>>(eA, aA, tb_index, edge_batch, angle_batch,
                                       wt_emp + (size_t)i*192*64, b_emp + i*64,
                                       afE1A, afE1B, afA1A, afA1B, msg, A);
    hipMemsetAsync(s1, 0, 2 * NG * 4, stream);
    k_red_e<<<2048, 256, 0, stream>>>(msg, eA, eA, ptr_e, perm_e, edge_batch,
                                      afE1A, afE1B, s1, s2, E);
    k_mkaff<<<4, 256, 0, stream>>>(s1, s2, cnt_e, 64, g_emp + i*64, be_emp + i*64, afE2A, afE2B);

    // 4. node_graph_mp: messages -> bf16 msg, CSR reduce (+stats) -> affX, apply
    k_mm_nmp<<<blkE, 256, 0, stream>>>(x_cur, eA, edge_index, edge_batch,
                                       wt_nmp + (size_t)i*320*128, b_nmp + i*128,
                                       afE2A, afE2B, msg, E);
    hipMemsetAsync(s1, 0, 2 * NG * 4, stream);
    k_red_n<<<2048, 256, 0, stream>>>(msg, x_cur, x_out, ptr_n, perm_n, node_batch,
                                      s1, s2, N);
    k_mkaff<<<8, 256, 0, stream>>>(s1, s2, cnt_n, 128, g_nmp + i*128, be_nmp + i*128, afXA, afXB);
    k_apply<<<2048, 256, 0, stream>>>(x_out, node_batch, afXA, afXB, (long)N * 128);

    x_cur = x_out;
  }
}